// Round 1
// baseline (2768.348 us; speedup 1.0000x reference)
//
#include <hip/hip_runtime.h>
#include <hip/hip_bf16.h>

// Problem constants (GQA): B=1, S=2048, D_MODEL=2048, NH=32, NKV=8, D_K=64
constexpr int S    = 2048;
constexpr int DM   = 2048;   // d_model
constexpr int HD   = 64;     // d_k per head
constexpr int NH   = 32;     // query heads
constexpr int NKV  = 8;      // kv heads
constexpr int DKV  = NKV * HD; // 512

// ---------------------------------------------------------------------------
// Generic fp32 GEMM + bias: C[M,N] = A[M,K] @ W[K,N] + bias[N]
// 64x64 tile, BK=16, 256 threads (16x16), 4x4 microtile per thread.
// Requires M%64==0, N%64==0, K%16==0 (true for all uses here).
// ---------------------------------------------------------------------------
__global__ __launch_bounds__(256) void gemm_bias_kernel(
    const float* __restrict__ A, const float* __restrict__ W,
    const float* __restrict__ bias, float* __restrict__ C,
    int M, int N, int K) {
  __shared__ float As[16][65];  // As[kk][m]
  __shared__ float Bs[16][65];  // Bs[kk][n]
  const int row0 = blockIdx.y * 64;
  const int col0 = blockIdx.x * 64;
  const int tx = threadIdx.x, ty = threadIdx.y;
  const int t = ty * 16 + tx;

  float acc[4][4] = {};
  for (int k0 = 0; k0 < K; k0 += 16) {
#pragma unroll
    for (int l = 0; l < 4; ++l) {
      int idx = t + l * 256;           // 0..1023
      int ar = idx >> 4, ac = idx & 15;    // A tile: 64 rows x 16 k
      As[ac][ar] = A[(size_t)(row0 + ar) * K + k0 + ac];
      int br = idx >> 6, bc = idx & 63;    // B tile: 16 k x 64 cols
      Bs[br][bc] = W[(size_t)(k0 + br) * N + col0 + bc];
    }
    __syncthreads();
#pragma unroll
    for (int kk = 0; kk < 16; ++kk) {
      float a[4], b[4];
#pragma unroll
      for (int i = 0; i < 4; ++i) a[i] = As[kk][ty * 4 + i];
#pragma unroll
      for (int j = 0; j < 4; ++j) b[j] = Bs[kk][tx * 4 + j];
#pragma unroll
      for (int i = 0; i < 4; ++i)
#pragma unroll
        for (int j = 0; j < 4; ++j) acc[i][j] += a[i] * b[j];
    }
    __syncthreads();
  }
#pragma unroll
  for (int i = 0; i < 4; ++i) {
#pragma unroll
    for (int j = 0; j < 4; ++j) {
      C[(size_t)(row0 + ty * 4 + i) * N + col0 + tx * 4 + j] =
          acc[i][j] + bias[col0 + tx * 4 + j];
    }
  }
}

// ---------------------------------------------------------------------------
// Scores: for head h, scores[h][qi][kj] = (Qp[qi, h*64:...] . Kp[kj, g*64:...]) / 8
// K-dim is exactly 64 -> load both 64x64 tiles fully into LDS once.
// Writes UNnormalized scores into attn buffer (softmax applied later).
// ---------------------------------------------------------------------------
__global__ __launch_bounds__(256) void scores_kernel(
    const float* __restrict__ Qp, const float* __restrict__ Kp,
    float* __restrict__ attn) {
  __shared__ float Qs[64][65];
  __shared__ float Ks[64][65];
  const int h = blockIdx.z;
  const int g = h >> 2;  // N_PER_KV = 4
  const int qi0 = blockIdx.y * 64;
  const int kj0 = blockIdx.x * 64;
  const int tx = threadIdx.x, ty = threadIdx.y;
  const int t = ty * 16 + tx;

#pragma unroll
  for (int l = 0; l < 16; ++l) {
    int idx = t + l * 256;           // 0..4095
    int r = idx >> 6, c = idx & 63;
    Qs[r][c] = Qp[(size_t)(qi0 + r) * DM + h * HD + c];
    Ks[r][c] = Kp[(size_t)(kj0 + r) * DKV + g * HD + c];
  }
  __syncthreads();

  float acc[4][4] = {};
#pragma unroll 8
  for (int kk = 0; kk < 64; ++kk) {
    float a[4], b[4];
#pragma unroll
    for (int i = 0; i < 4; ++i) a[i] = Qs[ty * 4 + i][kk];
#pragma unroll
    for (int j = 0; j < 4; ++j) b[j] = Ks[tx * 4 + j][kk];
#pragma unroll
    for (int i = 0; i < 4; ++i)
#pragma unroll
      for (int j = 0; j < 4; ++j) acc[i][j] += a[i] * b[j];
  }

  float* base = attn + (size_t)h * S * S;
#pragma unroll
  for (int i = 0; i < 4; ++i)
#pragma unroll
    for (int j = 0; j < 4; ++j)
      base[(size_t)(qi0 + ty * 4 + i) * S + kj0 + tx * 4 + j] =
          acc[i][j] * 0.125f;  // 1/sqrt(64)
}

// ---------------------------------------------------------------------------
// Row softmax in-place on attn: one block per row (NH*S rows, each 2048 wide).
// ---------------------------------------------------------------------------
__global__ __launch_bounds__(256) void softmax_kernel(float* __restrict__ attn) {
  __shared__ float buf[2048];
  __shared__ float red[256];
  const size_t row = blockIdx.x;
  float* p = attn + row * (size_t)S;
  const int t = threadIdx.x;

  float m = -1e30f;
  for (int i = t; i < S; i += 256) {
    float v = p[i];
    buf[i] = v;
    m = fmaxf(m, v);
  }
  red[t] = m;
  __syncthreads();
  for (int s = 128; s > 0; s >>= 1) {
    if (t < s) red[t] = fmaxf(red[t], red[t + s]);
    __syncthreads();
  }
  const float mx = red[0];
  __syncthreads();

  float sum = 0.f;
  for (int i = t; i < S; i += 256) {
    float e = __expf(buf[i] - mx);
    buf[i] = e;
    sum += e;
  }
  red[t] = sum;
  __syncthreads();
  for (int s = 128; s > 0; s >>= 1) {
    if (t < s) red[t] += red[t + s];
    __syncthreads();
  }
  const float inv = 1.0f / red[0];
  for (int i = t; i < S; i += 256) p[i] = buf[i] * inv;
}

// ---------------------------------------------------------------------------
// PV: AV[i, h*64+d] = sum_j attn[h,i,j] * Vp[j, g*64+d]
// Per head: M=S, N=64 (full), K=S. 64x64 tile, BK=16.
// ---------------------------------------------------------------------------
__global__ __launch_bounds__(256) void pv_kernel(
    const float* __restrict__ attn, const float* __restrict__ Vp,
    float* __restrict__ AV) {
  __shared__ float As[16][65];  // As[kk][m]
  __shared__ float Bs[16][65];  // Bs[kk][d]
  const int h = blockIdx.y;
  const int g = h >> 2;
  const int i0 = blockIdx.x * 64;
  const float* Ah = attn + (size_t)h * S * S;
  const int tx = threadIdx.x, ty = threadIdx.y;
  const int t = ty * 16 + tx;

  float acc[4][4] = {};
  for (int k0 = 0; k0 < S; k0 += 16) {
#pragma unroll
    for (int l = 0; l < 4; ++l) {
      int idx = t + l * 256;
      int ar = idx >> 4, ac = idx & 15;    // A tile: 64 (i) x 16 (j)
      As[ac][ar] = Ah[(size_t)(i0 + ar) * S + k0 + ac];
      int br = idx >> 6, bc = idx & 63;    // B tile: 16 (j) x 64 (d)
      Bs[br][bc] = Vp[(size_t)(k0 + br) * DKV + g * HD + bc];
    }
    __syncthreads();
#pragma unroll
    for (int kk = 0; kk < 16; ++kk) {
      float a[4], b[4];
#pragma unroll
      for (int i = 0; i < 4; ++i) a[i] = As[kk][ty * 4 + i];
#pragma unroll
      for (int j = 0; j < 4; ++j) b[j] = Bs[kk][tx * 4 + j];
#pragma unroll
      for (int i = 0; i < 4; ++i)
#pragma unroll
        for (int j = 0; j < 4; ++j) acc[i][j] += a[i] * b[j];
    }
    __syncthreads();
  }
#pragma unroll
  for (int i = 0; i < 4; ++i)
#pragma unroll
    for (int j = 0; j < 4; ++j)
      AV[(size_t)(i0 + ty * 4 + i) * DM + h * HD + tx * 4 + j] = acc[i][j];
}

// ---------------------------------------------------------------------------
extern "C" void kernel_launch(void* const* d_in, const int* in_sizes, int n_in,
                              void* d_out, int out_size, void* d_ws, size_t ws_size,
                              hipStream_t stream) {
  const float* q  = (const float*)d_in[0];
  const float* k  = (const float*)d_in[1];
  const float* v  = (const float*)d_in[2];
  // d_in[3] = mask: all-true in this problem -> no-op in the reference; ignored.
  const float* wq = (const float*)d_in[4];
  const float* bq = (const float*)d_in[5];
  const float* wk = (const float*)d_in[6];
  const float* bk = (const float*)d_in[7];
  const float* wv = (const float*)d_in[8];
  const float* bv = (const float*)d_in[9];
  const float* wo = (const float*)d_in[10];
  const float* bo = (const float*)d_in[11];

  float* out0 = (float*)d_out;                       // [S, DM]
  float* attn = out0 + (size_t)S * DM;               // [NH, S, S]

  // Workspace: Qp[S,DM] + Kp[S,DKV] + Vp[S,DKV] + AV[S,DM]  (40 MB total)
  float* Qp = (float*)d_ws;
  float* Kp = Qp + (size_t)S * DM;
  float* Vp = Kp + (size_t)S * DKV;
  float* AV = Vp + (size_t)S * DKV;

  dim3 blk(16, 16);

  // 1-3: projections
  gemm_bias_kernel<<<dim3(DM / 64, S / 64), blk, 0, stream>>>(q, wq, bq, Qp, S, DM, DM);
  gemm_bias_kernel<<<dim3(DKV / 64, S / 64), blk, 0, stream>>>(k, wk, bk, Kp, S, DKV, DM);
  gemm_bias_kernel<<<dim3(DKV / 64, S / 64), blk, 0, stream>>>(v, wv, bv, Vp, S, DKV, DM);

  // 4: scores (unnormalized) into attn output region
  scores_kernel<<<dim3(S / 64, S / 64, NH), blk, 0, stream>>>(Qp, Kp, attn);

  // 5: softmax in-place (this IS output 1)
  softmax_kernel<<<dim3(NH * S), dim3(256), 0, stream>>>(attn);

  // 6: PV
  pv_kernel<<<dim3(S / 64, NH), blk, 0, stream>>>(attn, Vp, AV);

  // 7: output projection
  gemm_bias_kernel<<<dim3(DM / 64, S / 64), blk, 0, stream>>>(AV, wo, bo, out0, S, DM, DM);
}